// Round 6
// baseline (580.117 us; speedup 1.0000x reference)
//
#include <hip/hip_runtime.h>
#include <stdint.h>

typedef unsigned short U16;
typedef __bf16 bf16x8 __attribute__((ext_vector_type(8)));
typedef unsigned short us8 __attribute__((ext_vector_type(8)));
typedef float f32x4 __attribute__((ext_vector_type(4)));

__device__ __forceinline__ U16 f2bf(float f) {
    unsigned u = __builtin_bit_cast(unsigned, f);
    unsigned r = (u + 0x7fff + ((u >> 16) & 1)) >> 16;
    return (U16)r;
}
__device__ __forceinline__ U16 f2bf_fast(float f) {   // round-half-up, for positive non-NaN
    return (U16)((__builtin_bit_cast(unsigned, f) + 0x8000u) >> 16);
}
__device__ __forceinline__ float bf2f(U16 v) {
    return __builtin_bit_cast(float, (unsigned)v << 16);
}
__device__ __forceinline__ bf16x8 ld8(const U16* p) { return __builtin_bit_cast(bf16x8, *(const us8*)p); }

// async global->LDS, 16B per lane; lds base wave-uniform, HW scatters lane i at base+i*16
__device__ __forceinline__ void async16(const U16* g, U16* l) {
    auto* gp = (const __attribute__((address_space(1))) U16*)g;
    auto* lp = (__attribute__((address_space(3))) U16*)(uintptr_t)(uint32_t)(uintptr_t)l;
    __builtin_amdgcn_global_load_lds(gp, lp, 16, 0, 0);
}

// ---------------- merged weight transpose: dst[noff+n][kk] = bf16(src[kk-koff][n]), zero-padded
struct WEnt { const float* src; U16* dst; int K, N, Kpad, Npad, koff, noff, tiles; };
struct WTable { WEnt e[13]; };

__global__ __launch_bounds__(256) void wtrans_all(WTable t) {
    int bx = blockIdx.x, ei = 0;
    while (bx >= t.e[ei].tiles) { bx -= t.e[ei].tiles; ei++; }
    const WEnt E = t.e[ei];
    const int ntn = E.Npad >> 5;
    const int n0 = (bx % ntn) * 32, k0 = (bx / ntn) * 32;
    __shared__ float tile[32][33];
    const int tx = threadIdx.x & 31, ty = threadIdx.x >> 5;
#pragma unroll
    for (int i = 0; i < 4; i++) {
        int kk = k0 + ty + i * 8, n = n0 + tx;
        int k = kk - E.koff;
        float v = (k >= 0 && k < E.K && n < E.N) ? E.src[(size_t)k * E.N + n] : 0.f;
        tile[ty + i * 8][tx] = v;
    }
    __syncthreads();
#pragma unroll
    for (int i = 0; i < 4; i++) {
        int n = n0 + ty + i * 8, kk = k0 + tx;
        E.dst[(size_t)(E.noff + n) * E.Kpad + kk] = f2bf(tile[tx][ty + i * 8]);
    }
}

// ---------------- fp32 -> bf16 convert
__global__ __launch_bounds__(256) void f2bf_k(const float* __restrict__ in, U16* __restrict__ out, int n) {
    int i = (blockIdx.x * 256 + threadIdx.x) * 4;
    if (i < n) {
        float4 v = *(const float4*)(in + i);
        out[i + 0] = f2bf(v.x); out[i + 1] = f2bf(v.y);
        out[i + 2] = f2bf(v.z); out[i + 3] = f2bf(v.w);
    }
}

// ---------------- RMSNorm: fp32 row (1024) -> bf16
__global__ __launch_bounds__(256) void rmsnorm_k(const float* __restrict__ x, const float* __restrict__ w,
                                                 U16* __restrict__ h) {
    const int row = blockIdx.x, tid = threadIdx.x;
    const float4 v = *(const float4*)(x + (size_t)row * 1024 + tid * 4);
    float ss = v.x * v.x + v.y * v.y + v.z * v.z + v.w * v.w;
#pragma unroll
    for (int o = 32; o > 0; o >>= 1) ss += __shfl_xor(ss, o);
    __shared__ float red[4];
    if ((tid & 63) == 0) red[tid >> 6] = ss;
    __syncthreads();
    float tot = red[0] + red[1] + red[2] + red[3];
    float sc = rsqrtf(tot * (1.0f / 1024.0f) + 1e-6f);
    const float4 wv = *(const float4*)(w + tid * 4);
    U16* hp = h + (size_t)row * 1024 + tid * 4;
    hp[0] = f2bf(v.x * sc * wv.x); hp[1] = f2bf(v.y * sc * wv.y);
    hp[2] = f2bf(v.z * sc * wv.z); hp[3] = f2bf(v.w * sc * wv.w);
}

// ---------------- 128x128 GEMM, double-panel K (logical BK=64): C = A[M,K] @ Bt[N,K]^T
// Split-K via gridDim.z (each block does K at offset blockIdx.z*K).
// EPI 0: bf16 C. EPI 2: bf16 transposed C[n*ldc+m] via per-wave LDS transpose (coalesced stores).
// EPI 4: atomicAdd fp32 into C (pre-zeroed); blockIdx.z==0 also adds resid.
template <int EPI>
__global__ __launch_bounds__(256) void gemm2(const U16* __restrict__ A, const U16* __restrict__ Bt,
                                             void* __restrict__ Cout, const float* __restrict__ resid,
                                             int M, int N, int K, int lda, int ldb, int ldc) {
    __shared__ __align__(16) U16 As[2][128 * 32];
    __shared__ __align__(16) U16 Bs[2][128 * 32];
    const int tid = threadIdx.x;
    const int m0 = blockIdx.y * 128, n0 = blockIdx.x * 128;
    const int k0 = blockIdx.z * K;
    const int wave = tid >> 6, lane = tid & 63, l16 = lane & 15, quad = lane >> 4;
    const int wm = (wave >> 1) * 64, wn = (wave & 1) * 64;
    const int sr = lane >> 2, sc = (lane & 3) * 8;
    const U16* gA = A + (size_t)(m0 + wave * 32 + sr) * lda + sc + k0;
    const U16* gB = Bt + (size_t)(n0 + wave * 32 + sr) * ldb + sc + k0;
    f32x4 acc[4][4] = {};
    for (int kt = 0; kt < K; kt += 64) {
        __syncthreads();
#pragma unroll
        for (int p = 0; p < 2; p++) {
            const int o = kt + p * 32;
            async16(gA + o, &As[p][(wave * 32) * 32]);
            async16(gA + (size_t)16 * lda + o, &As[p][(wave * 32 + 16) * 32]);
            async16(gB + o, &Bs[p][(wave * 32) * 32]);
            async16(gB + (size_t)16 * ldb + o, &Bs[p][(wave * 32 + 16) * 32]);
        }
        __syncthreads();
#pragma unroll
        for (int p = 0; p < 2; p++) {
            bf16x8 af[4], bfr[4];
#pragma unroll
            for (int i = 0; i < 4; i++) {
                af[i]  = ld8(&As[p][(wm + i * 16 + l16) * 32 + quad * 8]);
                bfr[i] = ld8(&Bs[p][(wn + i * 16 + l16) * 32 + quad * 8]);
            }
#pragma unroll
            for (int mi = 0; mi < 4; mi++)
#pragma unroll
                for (int ni = 0; ni < 4; ni++)
                    acc[mi][ni] = __builtin_amdgcn_mfma_f32_16x16x32_bf16(af[mi], bfr[ni], acc[mi][ni], 0, 0, 0);
        }
    }
    if constexpr (EPI == 2) {
        // per-wave LDS transpose -> coalesced 16B stores along m
        __shared__ __align__(16) U16 Ts[4][64 * 80];
        U16* T = Ts[wave];
#pragma unroll
        for (int mi = 0; mi < 4; mi++)
#pragma unroll
            for (int ni = 0; ni < 4; ni++)
#pragma unroll
                for (int r = 0; r < 4; r++)
                    T[(ni * 16 + l16) * 80 + mi * 16 + quad * 4 + r] = f2bf(acc[mi][ni][r]);
        // same-wave DS ordering; compiler inserts lgkmcnt wait
#pragma unroll
        for (int c = 0; c < 8; c++) {
            int nloc = (lane >> 3) + 8 * c, mloc = (lane & 7) * 8;
            us8 v = *(const us8*)&T[nloc * 80 + mloc];
            *(us8*)&((U16*)Cout)[(size_t)(n0 + wn + nloc) * ldc + (m0 + wm + mloc)] = v;
        }
    } else {
#pragma unroll
        for (int mi = 0; mi < 4; mi++) {
#pragma unroll
            for (int r = 0; r < 4; r++) {
                int m = m0 + wm + mi * 16 + quad * 4 + r;
#pragma unroll
                for (int ni = 0; ni < 4; ni++) {
                    int n = n0 + wn + ni * 16 + l16;
                    float val = acc[mi][ni][r];
                    if (EPI == 0) ((U16*)Cout)[(size_t)m * ldc + n] = f2bf(val);
                    else if (EPI == 4) {
                        if (blockIdx.z == 0) val += resid[(size_t)m * ldc + n];
                        atomicAdd(&((float*)Cout)[(size_t)m * ldc + n], val);
                    }
                }
            }
        }
    }
}

// ---------------- 64x128 GEMM, quad-panel K (logical BK=128); EPI 0 bf16 / 1 fp32+resid / 3 atomicAdd
template <int EPI>
__global__ __launch_bounds__(256) void gemm_m64(const U16* __restrict__ A, const U16* __restrict__ Bt,
                                                void* __restrict__ Cout, const float* __restrict__ resid,
                                                int M, int N, int K, int lda, int ldb, int ldc) {
    __shared__ __align__(16) U16 As[4][64 * 32];
    __shared__ __align__(16) U16 Bs[4][128 * 32];
    const int tid = threadIdx.x;
    const int m0 = blockIdx.y * 64, n0 = blockIdx.x * 128;
    const int k0 = blockIdx.z * K;
    const int wave = tid >> 6, lane = tid & 63, l16 = lane & 15, quad = lane >> 4;
    const int wm = (wave >> 1) * 32, wn = (wave & 1) * 64;
    const int sr = lane >> 2, sc = (lane & 3) * 8;
    const U16* gA = A + (size_t)(m0 + wave * 16 + sr) * lda + sc + k0;
    const U16* gB = Bt + (size_t)(n0 + wave * 32 + sr) * ldb + sc + k0;
    f32x4 acc[2][4] = {};
    for (int kt = 0; kt < K; kt += 128) {
        __syncthreads();
#pragma unroll
        for (int p = 0; p < 4; p++) {
            const int o = kt + p * 32;
            async16(gA + o, &As[p][(wave * 16) * 32]);
            async16(gB + o, &Bs[p][(wave * 32) * 32]);
            async16(gB + (size_t)16 * ldb + o, &Bs[p][(wave * 32 + 16) * 32]);
        }
        __syncthreads();
#pragma unroll
        for (int p = 0; p < 4; p++) {
            bf16x8 af[2], bfr[4];
#pragma unroll
            for (int i = 0; i < 2; i++)
                af[i] = ld8(&As[p][(wm + i * 16 + l16) * 32 + quad * 8]);
#pragma unroll
            for (int i = 0; i < 4; i++)
                bfr[i] = ld8(&Bs[p][(wn + i * 16 + l16) * 32 + quad * 8]);
#pragma unroll
            for (int mi = 0; mi < 2; mi++)
#pragma unroll
                for (int ni = 0; ni < 4; ni++)
                    acc[mi][ni] = __builtin_amdgcn_mfma_f32_16x16x32_bf16(af[mi], bfr[ni], acc[mi][ni], 0, 0, 0);
        }
    }
#pragma unroll
    for (int mi = 0; mi < 2; mi++) {
#pragma unroll
        for (int r = 0; r < 4; r++) {
            int m = m0 + wm + mi * 16 + quad * 4 + r;
#pragma unroll
            for (int ni = 0; ni < 4; ni++) {
                int n = n0 + wn + ni * 16 + l16;
                float val = acc[mi][ni][r];
                if (EPI == 0) ((U16*)Cout)[(size_t)m * ldc + n] = f2bf(val);
                else if (EPI == 1) ((float*)Cout)[(size_t)m * ldc + n] = resid[(size_t)m * ldc + n] + val;
                else if (EPI == 3) atomicAdd(&((float*)Cout)[(size_t)m * ldc + n], val);
            }
        }
    }
}

// ---------------- fused FFN1: act = silu(A@Wg^T) * (A@Wu^T)
// 128m x 64n output tile, BOTH gate and up accumulators (gemm2 resource budget).
__global__ __launch_bounds__(256) void ffn1_fused(const U16* __restrict__ A, const U16* __restrict__ Wgu,
                                                  U16* __restrict__ Cout) {
    __shared__ __align__(16) U16 As[2][128 * 32];
    __shared__ __align__(16) U16 Gs[2][64 * 32];
    __shared__ __align__(16) U16 Us[2][64 * 32];
    const int tid = threadIdx.x;
    const int m0 = blockIdx.y * 128, n0 = blockIdx.x * 64;
    const int wave = tid >> 6, lane = tid & 63, l16 = lane & 15, quad = lane >> 4;
    const int wm = (wave >> 1) * 64, wn = (wave & 1) * 32;
    const int sr = lane >> 2, sc = (lane & 3) * 8;
    const U16* gA = A + (size_t)(m0 + wave * 32 + sr) * 1024 + sc;
    const U16* gG = Wgu + (size_t)(n0 + wave * 16 + sr) * 1024 + sc;
    const U16* gU = gG + (size_t)4096 * 1024;
    f32x4 ag[4][2] = {}, au[4][2] = {};
    for (int kt = 0; kt < 1024; kt += 64) {
        __syncthreads();
#pragma unroll
        for (int p = 0; p < 2; p++) {
            const int o = kt + p * 32;
            async16(gA + o, &As[p][(wave * 32) * 32]);
            async16(gA + 16 * 1024 + o, &As[p][(wave * 32 + 16) * 32]);
            async16(gG + o, &Gs[p][(wave * 16) * 32]);
            async16(gU + o, &Us[p][(wave * 16) * 32]);
        }
        __syncthreads();
#pragma unroll
        for (int p = 0; p < 2; p++) {
            bf16x8 af[4], bg[2], bu[2];
#pragma unroll
            for (int i = 0; i < 4; i++)
                af[i] = ld8(&As[p][(wm + i * 16 + l16) * 32 + quad * 8]);
#pragma unroll
            for (int i = 0; i < 2; i++) {
                bg[i] = ld8(&Gs[p][(wn + i * 16 + l16) * 32 + quad * 8]);
                bu[i] = ld8(&Us[p][(wn + i * 16 + l16) * 32 + quad * 8]);
            }
#pragma unroll
            for (int mi = 0; mi < 4; mi++)
#pragma unroll
                for (int ni = 0; ni < 2; ni++) {
                    ag[mi][ni] = __builtin_amdgcn_mfma_f32_16x16x32_bf16(af[mi], bg[ni], ag[mi][ni], 0, 0, 0);
                    au[mi][ni] = __builtin_amdgcn_mfma_f32_16x16x32_bf16(af[mi], bu[ni], au[mi][ni], 0, 0, 0);
                }
        }
    }
#pragma unroll
    for (int mi = 0; mi < 4; mi++) {
#pragma unroll
        for (int r = 0; r < 4; r++) {
            int m = m0 + wm + mi * 16 + quad * 4 + r;
#pragma unroll
            for (int ni = 0; ni < 2; ni++) {
                int n = n0 + wn + ni * 16 + l16;
                float g = ag[mi][ni][r], u = au[mi][ni][r];
                float act = g / (1.f + __expf(-g)) * u;
                Cout[(size_t)m * 4096 + n] = f2bf(act);
            }
        }
    }
}

// ---------------- flash self-attention, j-parallel (linear accumulation, no online max)
__global__ __launch_bounds__(256) void flash_self3(const U16* __restrict__ QK, const U16* __restrict__ Vt,
                                                   U16* __restrict__ Og) {
    __shared__ __align__(16) U16 Ps[4 * 1280];
    __shared__ float Ored[4 * 2080];
    __shared__ float Lred[128];
    const int wave = threadIdx.x >> 6, lane = threadIdx.x & 63;
    const int l16 = lane & 15, quad = lane >> 4;
    const int bx = blockIdx.x;
    const int t = 63 - (bx >> 5);
    const int bh = bx & 31, b = bh >> 4, h = bh & 15;
    const int q0 = t * 32;
    const size_t rowQ0 = (size_t)(b * 2048 + q0 + l16) * 2048 + h * 64;
    const size_t rowQ1 = rowQ0 + 16 * 2048;
    bf16x8 aq[2][2];
    aq[0][0] = ld8(QK + rowQ0 + quad * 8);  aq[0][1] = ld8(QK + rowQ0 + 32 + quad * 8);
    aq[1][0] = ld8(QK + rowQ1 + quad * 8);  aq[1][1] = ld8(QK + rowQ1 + 32 + quad * 8);
    const U16* Kbase = QK + (size_t)(b * 2048) * 2048 + 1024 + h * 64;
    const U16* Vbase = Vt + (size_t)(h * 64) * 4096 + b * 2048;
    f32x4 o[2][4] = {};
    float ls[2][4] = {};
    U16* Pw = &Ps[wave * 1280];
    const int prd = l16 * 40 + ((quad ^ (l16 >> 2)) << 3);
    const int jend = q0 + 32;
    for (int j0 = wave * 32; j0 < jend; j0 += 128) {
        const U16* kp = Kbase + (size_t)j0 * 2048;
        bf16x8 b00 = ld8(kp + (size_t)l16 * 2048 + quad * 8);
        bf16x8 b01 = ld8(kp + (size_t)l16 * 2048 + 32 + quad * 8);
        bf16x8 b10 = ld8(kp + (size_t)(16 + l16) * 2048 + quad * 8);
        bf16x8 b11 = ld8(kp + (size_t)(16 + l16) * 2048 + 32 + quad * 8);
        bf16x8 v0 = ld8(Vbase + (size_t)(0  + l16) * 4096 + j0 + quad * 8);
        bf16x8 v1 = ld8(Vbase + (size_t)(16 + l16) * 4096 + j0 + quad * 8);
        bf16x8 v2 = ld8(Vbase + (size_t)(32 + l16) * 4096 + j0 + quad * 8);
        bf16x8 v3 = ld8(Vbase + (size_t)(48 + l16) * 4096 + j0 + quad * 8);
        f32x4 s[2][2] = {};
#pragma unroll
        for (int g = 0; g < 2; g++) {
            s[g][0] = __builtin_amdgcn_mfma_f32_16x16x32_bf16(aq[g][0], b00, s[g][0], 0, 0, 0);
            s[g][0] = __builtin_amdgcn_mfma_f32_16x16x32_bf16(aq[g][1], b01, s[g][0], 0, 0, 0);
            s[g][1] = __builtin_amdgcn_mfma_f32_16x16x32_bf16(aq[g][0], b10, s[g][1], 0, 0, 0);
            s[g][1] = __builtin_amdgcn_mfma_f32_16x16x32_bf16(aq[g][1], b11, s[g][1], 0, 0, 0);
        }
        float p0[2][4], p1[2][4];
        if (j0 + 32 >= jend) {
#pragma unroll
            for (int g = 0; g < 2; g++)
#pragma unroll
                for (int r = 0; r < 4; r++) {
                    int qg = q0 + g * 16 + quad * 4 + r;
                    p0[g][r] = (j0 + l16 <= qg) ? __expf(fminf(s[g][0][r] * 0.125f, 30.f)) : 0.f;
                    p1[g][r] = (j0 + 16 + l16 <= qg) ? __expf(fminf(s[g][1][r] * 0.125f, 30.f)) : 0.f;
                }
        } else {
#pragma unroll
            for (int g = 0; g < 2; g++)
#pragma unroll
                for (int r = 0; r < 4; r++) {
                    p0[g][r] = __expf(fminf(s[g][0][r] * 0.125f, 30.f));
                    p1[g][r] = __expf(fminf(s[g][1][r] * 0.125f, 30.f));
                }
        }
#pragma unroll
        for (int g = 0; g < 2; g++)
#pragma unroll
            for (int r = 0; r < 4; r++) {
                ls[g][r] += p0[g][r] + p1[g][r];
                int row = quad * 4 + r;
                Pw[g * 640 + row * 40 + ((((l16 >> 3) + 0) ^ quad) << 3) + (l16 & 7)] = f2bf_fast(p0[g][r]);
                Pw[g * 640 + row * 40 + ((((l16 >> 3) + 2) ^ quad) << 3) + (l16 & 7)] = f2bf_fast(p1[g][r]);
            }
#pragma unroll
        for (int g = 0; g < 2; g++) {
            bf16x8 ap = ld8(&Pw[g * 640 + prd]);
            o[g][0] = __builtin_amdgcn_mfma_f32_16x16x32_bf16(ap, v0, o[g][0], 0, 0, 0);
            o[g][1] = __builtin_amdgcn_mfma_f32_16x16x32_bf16(ap, v1, o[g][1], 0, 0, 0);
            o[g][2] = __builtin_amdgcn_mfma_f32_16x16x32_bf16(ap, v2, o[g][2], 0, 0, 0);
            o[g][3] = __builtin_amdgcn_mfma_f32_16x16x32_bf16(ap, v3, o[g][3], 0, 0, 0);
        }
    }
    float* Or = &Ored[wave * 2080];
#pragma unroll
    for (int g = 0; g < 2; g++) {
#pragma unroll
        for (int dg = 0; dg < 4; dg++)
#pragma unroll
            for (int r = 0; r < 4; r++)
                Or[(g * 16 + quad * 4 + r) * 65 + dg * 16 + l16] = o[g][dg][r];
#pragma unroll
        for (int r = 0; r < 4; r++) {
            float v = ls[g][r];
            v += __shfl_xor(v, 1); v += __shfl_xor(v, 2);
            v += __shfl_xor(v, 4); v += __shfl_xor(v, 8);
            if (l16 == 0) Lred[wave * 32 + g * 16 + quad * 4 + r] = v;
        }
    }
    __syncthreads();
    const int q = threadIdx.x >> 3, d0 = (threadIdx.x & 7) * 8;
    float l = Lred[q] + Lred[32 + q] + Lred[64 + q] + Lred[96 + q];
    float inv = 1.0f / l;
    us8 outv;
#pragma unroll
    for (int i = 0; i < 8; i++) {
        int idx = q * 65 + d0 + i;
        float s = Ored[idx] + Ored[2080 + idx] + Ored[4160 + idx] + Ored[6240 + idx];
        outv[i] = f2bf(s * inv);
    }
    *(us8*)(Og + (size_t)(b * 2048 + q0 + q) * 1024 + h * 64 + d0) = outv;
}

// ---------------- sliding-window cross attention (9 kv per query)
__global__ __launch_bounds__(256) void cross_attn(const U16* __restrict__ qc, const U16* __restrict__ kvc,
                                                  const int* __restrict__ seg_ids, U16* __restrict__ oc) {
    const int tok = blockIdx.x;
    const int b = tok >> 11;
    const int w = threadIdx.x >> 6, lane = threadIdx.x & 63;
    const int h = blockIdx.y * 4 + w;
    const int seg = seg_ids[tok];
    const size_t qoff = (size_t)tok * 1024 + h * 64 + lane;
    float q = bf2f(qc[qoff]);
    float s[9];
#pragma unroll
    for (int jj = 0; jj < 9; jj++) {
        int j = seg - 8 + jj;
        float sc = -INFINITY;
        if (j >= 0) {
            float kv = bf2f(kvc[((size_t)(b * 512) + j) * 2048 + h * 64 + lane]);
            sc = q * kv;
            sc += __shfl_xor(sc, 1); sc += __shfl_xor(sc, 2); sc += __shfl_xor(sc, 4);
            sc += __shfl_xor(sc, 8); sc += __shfl_xor(sc, 16); sc += __shfl_xor(sc, 32);
            sc *= 0.125f;
        }
        s[jj] = sc;
    }
    float m = s[0];
#pragma unroll
    for (int jj = 1; jj < 9; jj++) m = fmaxf(m, s[jj]);
    float l = 0.f, o = 0.f;
#pragma unroll
    for (int jj = 0; jj < 9; jj++) {
        int j = seg - 8 + jj;
        if (j >= 0) {
            float p = __expf(s[jj] - m);
            l += p;
            o += p * bf2f(kvc[((size_t)(b * 512) + j) * 2048 + 1024 + h * 64 + lane]);
        }
    }
    oc[qoff] = f2bf(o / l);
}

extern "C" void kernel_launch(void* const* d_in, const int* in_sizes, int n_in,
                              void* d_out, int out_size, void* d_ws, size_t ws_size,
                              hipStream_t stream) {
    const float* x      = (const float*)d_in[0];
    const float* memory = (const float*)d_in[1];
    const int*   seg    = (const int*)d_in[2];
    const float* n1w    = (const float*)d_in[3];
    const float* W_dq   = (const float*)d_in[4];
    const float* W_uq   = (const float*)d_in[5];
    const float* W_dkv  = (const float*)d_in[6];
    const float* W_uk   = (const float*)d_in[7];
    const float* W_uv   = (const float*)d_in[8];
    const float* W_os   = (const float*)d_in[9];
    const float* n2w    = (const float*)d_in[10];
    const float* W_qc   = (const float*)d_in[11];
    const float* W_kc   = (const float*)d_in[12];
    const float* W_vc   = (const float*)d_in[13];
    const float* W_oc   = (const float*)d_in[14];
    const float* n3w    = (const float*)d_in[15];
    const float* W_gate = (const float*)d_in[16];
    const float* W_up   = (const float*)d_in[17];
    const float* W_down = (const float*)d_in[18];
    (void)in_sizes; (void)n_in; (void)out_size; (void)ws_size;

    char* ws = (char*)d_ws;
    size_t off = 0;
    auto alloc = [&](size_t bytes) -> void* {
        void* p = ws + off;
        off += (bytes + 255) & ~(size_t)255;
        return p;
    };
    const size_t MB = 1024 * 1024;
    U16* hbuf     = (U16*)alloc(8 * MB);
    float* x1     = (float*)alloc(16 * MB);
    float* x2     = (float*)alloc(16 * MB);
    float* cq32   = (float*)alloc(2 * MB);
    U16* Wt_dqkv  = (U16*)alloc(128 * 1024 * 2);
    U16* Wt_uqk   = (U16*)alloc(2048 * 128 * 2);
    U16* Wt_uv    = (U16*)alloc(1024 * 128 * 2);
    U16* Wt_os    = (U16*)alloc(1024 * 1024 * 2);
    U16* Wt_qc    = (U16*)alloc(1024 * 1024 * 2);
    U16* Wt_kvc   = (U16*)alloc((size_t)2048 * 1024 * 2);
    U16* Wt_oc    = (U16*)alloc(1024 * 1024 * 2);
    U16* Wt_gu    = (U16*)alloc((size_t)8192 * 1024 * 2);
    U16* Wt_down  = (U16*)alloc((size_t)1024 * 4096 * 2);
    U16* mem_bf   = (U16*)alloc(1024 * 1024 * 2);
    char* arena   = ws + off;
    // phase 1
    U16* cq  = (U16*)(arena);                  // [4096][128]
    U16* qkb = (U16*)(arena + 1 * MB);         // [4096][2048]
    U16* vt  = (U16*)(arena + 17 * MB);        // [1024][4096]
    U16* ob  = (U16*)(arena + 25 * MB);        // [4096][1024]
    // phase 2
    U16* qcb  = (U16*)(arena);                 // [4096][1024]
    U16* kvcb = (U16*)(arena + 8 * MB);        // [1024][2048]
    U16* ocb  = (U16*)(arena + 12 * MB);       // [4096][1024]
    // phase 3
    U16* gact = (U16*)(arena);                 // [4096][4096]

    // ---- merged weight prep
    WTable T;
    int i = 0;
    auto ent = [&](const float* s, U16* d, int K, int N, int Kpad, int Npad, int koff, int noff) {
        T.e[i++] = WEnt{s, d, K, N, Kpad, Npad, koff, noff, (Kpad >> 5) * (Npad >> 5)};
    };
    ent(W_dq,   Wt_dqkv, 1024, 32,   1024, 32,   0,  0);
    ent(W_dkv,  Wt_dqkv, 1024, 64,   1024, 96,   0,  32);
    ent(W_uq,   Wt_uqk,  32,   1024, 128,  1024, 0,  0);
    ent(W_uk,   Wt_uqk,  64,   1024, 128,  1024, 32, 1024);
    ent(W_uv,   Wt_uv,   64,   1024, 128,  1024, 32, 0);
    ent(W_os,   Wt_os,   1024, 1024, 1024, 1024, 0,  0);
    ent(W_qc,   Wt_qc,   1024, 1024, 1024, 1024, 0,  0);
    ent(W_kc,   Wt_kvc,  1024, 1024, 1024, 1024, 0,  0);
    ent(W_vc,   Wt_kvc,  1024, 1024, 1024, 1024, 0,  1024);
    ent(W_oc,   Wt_oc,   1024, 1024, 1024, 1024, 0,  0);
    ent(W_gate, Wt_gu,   1024, 4096, 1024, 4096, 0,  0);
    ent(W_up,   Wt_gu,   1024, 4096, 1024, 4096, 0,  4096);
    ent(W_down, Wt_down, 4096, 1024, 4096, 1024, 0,  0);
    int total_tiles = 0;
    for (int j = 0; j < 13; j++) total_tiles += T.e[j].tiles;
    wtrans_all<<<total_tiles, 256, 0, stream>>>(T);
    f2bf_k<<<1024, 256, 0, stream>>>(memory, mem_bf, 1024 * 1024);
    hipMemsetAsync(cq32, 0, (size_t)4096 * 128 * 4, stream);
    hipMemsetAsync(d_out, 0, (size_t)4096 * 1024 * 4, stream);   // split-K accumulator for down

    // ---- phase 1: self-attention block
    rmsnorm_k<<<4096, 256, 0, stream>>>(x, n1w, hbuf);
    gemm_m64<3><<<dim3(1, 64, 4), 256, 0, stream>>>(hbuf, Wt_dqkv, cq32, nullptr, 4096, 128, 256, 1024, 1024, 128);
    f2bf_k<<<512, 256, 0, stream>>>(cq32, cq, 4096 * 128);
    gemm2<0><<<dim3(16, 32), 256, 0, stream>>>(cq, Wt_uqk, qkb, nullptr, 4096, 2048, 128, 128, 128, 2048);
    gemm2<2><<<dim3(8, 32),  256, 0, stream>>>(cq, Wt_uv,  vt,  nullptr, 4096, 1024, 128, 128, 128, 4096);
    flash_self3<<<2048, 256, 0, stream>>>(qkb, vt, ob);
    gemm_m64<1><<<dim3(8, 64), 256, 0, stream>>>(ob, Wt_os, x1, x, 4096, 1024, 1024, 1024, 1024, 1024);

    // ---- phase 2: cross attention block
    rmsnorm_k<<<4096, 256, 0, stream>>>(x1, n2w, hbuf);
    gemm_m64<0><<<dim3(8, 64),  256, 0, stream>>>(hbuf,   Wt_qc,  qcb,  nullptr, 4096, 1024, 1024, 1024, 1024, 1024);
    gemm_m64<0><<<dim3(16, 16), 256, 0, stream>>>(mem_bf, Wt_kvc, kvcb, nullptr, 1024, 2048, 1024, 1024, 1024, 2048);
    cross_attn<<<dim3(4096, 4), 256, 0, stream>>>(qcb, kvcb, seg, ocb);
    gemm_m64<1><<<dim3(8, 64),  256, 0, stream>>>(ocb,    Wt_oc,  x2,   x1,      4096, 1024, 1024, 1024, 1024, 1024);

    // ---- phase 3: FFN (fused gate+up+silu, then down via 128-tile split-K2 atomic)
    rmsnorm_k<<<4096, 256, 0, stream>>>(x2, n3w, hbuf);
    ffn1_fused<<<dim3(64, 32), 256, 0, stream>>>(hbuf, Wt_gu, gact);
    gemm2<4><<<dim3(8, 32, 2), 256, 0, stream>>>(gact, Wt_down, (float*)d_out, x2, 4096, 1024, 2048, 4096, 4096, 1024);
}

// Round 7
// 526.401 us; speedup vs baseline: 1.1020x; 1.1020x over previous
//
#include <hip/hip_runtime.h>
#include <stdint.h>

typedef unsigned short U16;
typedef __bf16 bf16x8 __attribute__((ext_vector_type(8)));
typedef unsigned short us8 __attribute__((ext_vector_type(8)));
typedef float f32x4 __attribute__((ext_vector_type(4)));

__device__ __forceinline__ U16 f2bf(float f) {
    unsigned u = __builtin_bit_cast(unsigned, f);
    unsigned r = (u + 0x7fff + ((u >> 16) & 1)) >> 16;
    return (U16)r;
}
__device__ __forceinline__ U16 f2bf_fast(float f) {   // round-half-up, for positive non-NaN
    return (U16)((__builtin_bit_cast(unsigned, f) + 0x8000u) >> 16);
}
__device__ __forceinline__ float bf2f(U16 v) {
    return __builtin_bit_cast(float, (unsigned)v << 16);
}
__device__ __forceinline__ bf16x8 ld8(const U16* p) { return __builtin_bit_cast(bf16x8, *(const us8*)p); }

// async global->LDS, 16B per lane; lds base wave-uniform, HW scatters lane i at base+i*16
__device__ __forceinline__ void async16(const U16* g, U16* l) {
    auto* gp = (const __attribute__((address_space(1))) U16*)g;
    auto* lp = (__attribute__((address_space(3))) U16*)(uintptr_t)(uint32_t)(uintptr_t)l;
    __builtin_amdgcn_global_load_lds(gp, lp, 16, 0, 0);
}

// ---------------- merged weight transpose: dst[noff+n][kk] = bf16(src[kk-koff][n]), zero-padded
struct WEnt { const float* src; U16* dst; int K, N, Kpad, Npad, koff, noff, tiles; };
struct WTable { WEnt e[13]; };

__global__ __launch_bounds__(256) void wtrans_all(WTable t) {
    int bx = blockIdx.x, ei = 0;
    while (bx >= t.e[ei].tiles) { bx -= t.e[ei].tiles; ei++; }
    const WEnt E = t.e[ei];
    const int ntn = E.Npad >> 5;
    const int n0 = (bx % ntn) * 32, k0 = (bx / ntn) * 32;
    __shared__ float tile[32][33];
    const int tx = threadIdx.x & 31, ty = threadIdx.x >> 5;
#pragma unroll
    for (int i = 0; i < 4; i++) {
        int kk = k0 + ty + i * 8, n = n0 + tx;
        int k = kk - E.koff;
        float v = (k >= 0 && k < E.K && n < E.N) ? E.src[(size_t)k * E.N + n] : 0.f;
        tile[ty + i * 8][tx] = v;
    }
    __syncthreads();
#pragma unroll
    for (int i = 0; i < 4; i++) {
        int n = n0 + ty + i * 8, kk = k0 + tx;
        E.dst[(size_t)(E.noff + n) * E.Kpad + kk] = f2bf(tile[tx][ty + i * 8]);
    }
}

// ---------------- fp32 -> bf16 convert
__global__ __launch_bounds__(256) void f2bf_k(const float* __restrict__ in, U16* __restrict__ out, int n) {
    int i = (blockIdx.x * 256 + threadIdx.x) * 4;
    if (i < n) {
        float4 v = *(const float4*)(in + i);
        out[i + 0] = f2bf(v.x); out[i + 1] = f2bf(v.y);
        out[i + 2] = f2bf(v.z); out[i + 3] = f2bf(v.w);
    }
}

// ---------------- reduce 4 fp32 partials [4][4096*128] -> bf16
__global__ __launch_bounds__(256) void cq_reduce(const float* __restrict__ p, U16* __restrict__ out) {
    int i = (blockIdx.x * 256 + threadIdx.x) * 4;
    const float4 a = *(const float4*)(p + i);
    const float4 b = *(const float4*)(p + 524288 + i);
    const float4 c = *(const float4*)(p + 2 * 524288 + i);
    const float4 d = *(const float4*)(p + 3 * 524288 + i);
    out[i + 0] = f2bf(a.x + b.x + c.x + d.x);
    out[i + 1] = f2bf(a.y + b.y + c.y + d.y);
    out[i + 2] = f2bf(a.z + b.z + c.z + d.z);
    out[i + 3] = f2bf(a.w + b.w + c.w + d.w);
}

// ---------------- RMSNorm: fp32 row (1024) -> bf16
__global__ __launch_bounds__(256) void rmsnorm_k(const float* __restrict__ x, const float* __restrict__ w,
                                                 U16* __restrict__ h) {
    const int row = blockIdx.x, tid = threadIdx.x;
    const float4 v = *(const float4*)(x + (size_t)row * 1024 + tid * 4);
    float ss = v.x * v.x + v.y * v.y + v.z * v.z + v.w * v.w;
#pragma unroll
    for (int o = 32; o > 0; o >>= 1) ss += __shfl_xor(ss, o);
    __shared__ float red[4];
    if ((tid & 63) == 0) red[tid >> 6] = ss;
    __syncthreads();
    float tot = red[0] + red[1] + red[2] + red[3];
    float sc = rsqrtf(tot * (1.0f / 1024.0f) + 1e-6f);
    const float4 wv = *(const float4*)(w + tid * 4);
    U16* hp = h + (size_t)row * 1024 + tid * 4;
    hp[0] = f2bf(v.x * sc * wv.x); hp[1] = f2bf(v.y * sc * wv.y);
    hp[2] = f2bf(v.z * sc * wv.z); hp[3] = f2bf(v.w * sc * wv.w);
}

// ---------------- merged uq/uk + uv GEMM from cq [4096][128], K=128
// grid (24, 32): x<16 -> qkb bf16 [4096][2048]; x>=16 -> vt transposed bf16 [1024][4096]
__global__ __launch_bounds__(256) void qkuv_gemm(const U16* __restrict__ A, const U16* __restrict__ Wuqk,
                                                 const U16* __restrict__ Wuv,
                                                 U16* __restrict__ qkb, U16* __restrict__ vt) {
    __shared__ __align__(16) U16 As[2][128 * 32];
    __shared__ __align__(16) U16 Bs[2][128 * 32];
    __shared__ __align__(16) U16 Ts[4][64 * 80];
    const int tid = threadIdx.x;
    const bool isuv = blockIdx.x >= 16;
    const U16* Bt = isuv ? Wuv : Wuqk;
    const int n0 = (isuv ? blockIdx.x - 16 : blockIdx.x) * 128;
    const int m0 = blockIdx.y * 128;
    const int wave = tid >> 6, lane = tid & 63, l16 = lane & 15, quad = lane >> 4;
    const int wm = (wave >> 1) * 64, wn = (wave & 1) * 64;
    const int sr = lane >> 2, sc = (lane & 3) * 8;
    const U16* gA = A + (size_t)(m0 + wave * 32 + sr) * 128 + sc;
    const U16* gB = Bt + (size_t)(n0 + wave * 32 + sr) * 128 + sc;
    f32x4 acc[4][4] = {};
    for (int kt = 0; kt < 128; kt += 64) {
        __syncthreads();
#pragma unroll
        for (int p = 0; p < 2; p++) {
            const int o = kt + p * 32;
            async16(gA + o, &As[p][(wave * 32) * 32]);
            async16(gA + 16 * 128 + o, &As[p][(wave * 32 + 16) * 32]);
            async16(gB + o, &Bs[p][(wave * 32) * 32]);
            async16(gB + 16 * 128 + o, &Bs[p][(wave * 32 + 16) * 32]);
        }
        __syncthreads();
#pragma unroll
        for (int p = 0; p < 2; p++) {
            bf16x8 af[4], bfr[4];
#pragma unroll
            for (int i = 0; i < 4; i++) {
                af[i]  = ld8(&As[p][(wm + i * 16 + l16) * 32 + quad * 8]);
                bfr[i] = ld8(&Bs[p][(wn + i * 16 + l16) * 32 + quad * 8]);
            }
#pragma unroll
            for (int mi = 0; mi < 4; mi++)
#pragma unroll
                for (int ni = 0; ni < 4; ni++)
                    acc[mi][ni] = __builtin_amdgcn_mfma_f32_16x16x32_bf16(af[mi], bfr[ni], acc[mi][ni], 0, 0, 0);
        }
    }
    if (isuv) {
        // per-wave LDS transpose -> coalesced 16B stores along m into vt [1024][4096]
        U16* T = Ts[wave];
#pragma unroll
        for (int mi = 0; mi < 4; mi++)
#pragma unroll
            for (int ni = 0; ni < 4; ni++)
#pragma unroll
                for (int r = 0; r < 4; r++)
                    T[(ni * 16 + l16) * 80 + mi * 16 + quad * 4 + r] = f2bf(acc[mi][ni][r]);
#pragma unroll
        for (int c = 0; c < 8; c++) {
            int nloc = (lane >> 3) + 8 * c, mloc = (lane & 7) * 8;
            us8 v = *(const us8*)&T[nloc * 80 + mloc];
            *(us8*)&vt[(size_t)(n0 + wn + nloc) * 4096 + (m0 + wm + mloc)] = v;
        }
    } else {
#pragma unroll
        for (int mi = 0; mi < 4; mi++)
#pragma unroll
            for (int r = 0; r < 4; r++) {
                int m = m0 + wm + mi * 16 + quad * 4 + r;
#pragma unroll
                for (int ni = 0; ni < 4; ni++)
                    qkb[(size_t)m * 2048 + n0 + wn + ni * 16 + l16] = f2bf(acc[mi][ni][r]);
            }
    }
}

// ---------------- 64x128 GEMM, quad-panel K (logical BK=128)
// EPI 0: bf16. EPI 1: fp32 = resid + acc. EPI 5: fp32 partial at Cout + z*524288 (no resid).
template <int EPI>
__global__ __launch_bounds__(256) void gemm_m64(const U16* __restrict__ A, const U16* __restrict__ Bt,
                                                void* __restrict__ Cout, const float* __restrict__ resid,
                                                int M, int N, int K, int lda, int ldb, int ldc) {
    __shared__ __align__(16) U16 As[4][64 * 32];
    __shared__ __align__(16) U16 Bs[4][128 * 32];
    const int tid = threadIdx.x;
    const int m0 = blockIdx.y * 64, n0 = blockIdx.x * 128;
    const int k0 = blockIdx.z * K;
    const int wave = tid >> 6, lane = tid & 63, l16 = lane & 15, quad = lane >> 4;
    const int wm = (wave >> 1) * 32, wn = (wave & 1) * 64;
    const int sr = lane >> 2, sc = (lane & 3) * 8;
    const U16* gA = A + (size_t)(m0 + wave * 16 + sr) * lda + sc + k0;
    const U16* gB = Bt + (size_t)(n0 + wave * 32 + sr) * ldb + sc + k0;
    f32x4 acc[2][4] = {};
    for (int kt = 0; kt < K; kt += 128) {
        __syncthreads();
#pragma unroll
        for (int p = 0; p < 4; p++) {
            const int o = kt + p * 32;
            async16(gA + o, &As[p][(wave * 16) * 32]);
            async16(gB + o, &Bs[p][(wave * 32) * 32]);
            async16(gB + (size_t)16 * ldb + o, &Bs[p][(wave * 32 + 16) * 32]);
        }
        __syncthreads();
#pragma unroll
        for (int p = 0; p < 4; p++) {
            bf16x8 af[2], bfr[4];
#pragma unroll
            for (int i = 0; i < 2; i++)
                af[i] = ld8(&As[p][(wm + i * 16 + l16) * 32 + quad * 8]);
#pragma unroll
            for (int i = 0; i < 4; i++)
                bfr[i] = ld8(&Bs[p][(wn + i * 16 + l16) * 32 + quad * 8]);
#pragma unroll
            for (int mi = 0; mi < 2; mi++)
#pragma unroll
                for (int ni = 0; ni < 4; ni++)
                    acc[mi][ni] = __builtin_amdgcn_mfma_f32_16x16x32_bf16(af[mi], bfr[ni], acc[mi][ni], 0, 0, 0);
        }
    }
#pragma unroll
    for (int mi = 0; mi < 2; mi++) {
#pragma unroll
        for (int r = 0; r < 4; r++) {
            int m = m0 + wm + mi * 16 + quad * 4 + r;
#pragma unroll
            for (int ni = 0; ni < 4; ni++) {
                int n = n0 + wn + ni * 16 + l16;
                float val = acc[mi][ni][r];
                if (EPI == 0) ((U16*)Cout)[(size_t)m * ldc + n] = f2bf(val);
                else if (EPI == 1) ((float*)Cout)[(size_t)m * ldc + n] = resid[(size_t)m * ldc + n] + val;
                else if (EPI == 5) ((float*)Cout)[(size_t)blockIdx.z * 524288 + (size_t)m * ldc + n] = val;
            }
        }
    }
}

// ---------------- merged qc + kvc GEMM (both EPI0, K=1024, lda=ldb=1024)
// 768 blocks: [0,512) -> qcb [4096][1024]; [512,768) -> kvcb [1024][2048]
__global__ __launch_bounds__(256) void qckv_gemm(const U16* __restrict__ hbuf, const U16* __restrict__ Wqc,
                                                 const U16* __restrict__ memb, const U16* __restrict__ Wkvc,
                                                 U16* __restrict__ qcb, U16* __restrict__ kvcb) {
    __shared__ __align__(16) U16 As[4][64 * 32];
    __shared__ __align__(16) U16 Bs[4][128 * 32];
    const int tid = threadIdx.x, bid = blockIdx.x;
    const U16 *A, *Bt; U16* C; int m0, n0, ldc;
    if (bid < 512) { A = hbuf; Bt = Wqc;  C = qcb;  m0 = (bid >> 3) * 64; n0 = (bid & 7) * 128;  ldc = 1024; }
    else { int b2 = bid - 512; A = memb; Bt = Wkvc; C = kvcb; m0 = (b2 >> 4) * 64; n0 = (b2 & 15) * 128; ldc = 2048; }
    const int wave = tid >> 6, lane = tid & 63, l16 = lane & 15, quad = lane >> 4;
    const int wm = (wave >> 1) * 32, wn = (wave & 1) * 64;
    const int sr = lane >> 2, sc = (lane & 3) * 8;
    const U16* gA = A + (size_t)(m0 + wave * 16 + sr) * 1024 + sc;
    const U16* gB = Bt + (size_t)(n0 + wave * 32 + sr) * 1024 + sc;
    f32x4 acc[2][4] = {};
    for (int kt = 0; kt < 1024; kt += 128) {
        __syncthreads();
#pragma unroll
        for (int p = 0; p < 4; p++) {
            const int o = kt + p * 32;
            async16(gA + o, &As[p][(wave * 16) * 32]);
            async16(gB + o, &Bs[p][(wave * 32) * 32]);
            async16(gB + 16 * 1024 + o, &Bs[p][(wave * 32 + 16) * 32]);
        }
        __syncthreads();
#pragma unroll
        for (int p = 0; p < 4; p++) {
            bf16x8 af[2], bfr[4];
#pragma unroll
            for (int i = 0; i < 2; i++)
                af[i] = ld8(&As[p][(wm + i * 16 + l16) * 32 + quad * 8]);
#pragma unroll
            for (int i = 0; i < 4; i++)
                bfr[i] = ld8(&Bs[p][(wn + i * 16 + l16) * 32 + quad * 8]);
#pragma unroll
            for (int mi = 0; mi < 2; mi++)
#pragma unroll
                for (int ni = 0; ni < 4; ni++)
                    acc[mi][ni] = __builtin_amdgcn_mfma_f32_16x16x32_bf16(af[mi], bfr[ni], acc[mi][ni], 0, 0, 0);
        }
    }
#pragma unroll
    for (int mi = 0; mi < 2; mi++)
#pragma unroll
        for (int r = 0; r < 4; r++) {
            int m = m0 + wm + mi * 16 + quad * 4 + r;
#pragma unroll
            for (int ni = 0; ni < 4; ni++)
                C[(size_t)m * ldc + n0 + wn + ni * 16 + l16] = f2bf(acc[mi][ni][r]);
        }
}

// ---------------- fused FFN1: act = silu(A@Wg^T) * (A@Wu^T), 128m x 64n dual tile
__global__ __launch_bounds__(256) void ffn1_fused(const U16* __restrict__ A, const U16* __restrict__ Wgu,
                                                  U16* __restrict__ Cout) {
    __shared__ __align__(16) U16 As[2][128 * 32];
    __shared__ __align__(16) U16 Gs[2][64 * 32];
    __shared__ __align__(16) U16 Us[2][64 * 32];
    const int tid = threadIdx.x;
    const int m0 = blockIdx.y * 128, n0 = blockIdx.x * 64;
    const int wave = tid >> 6, lane = tid & 63, l16 = lane & 15, quad = lane >> 4;
    const int wm = (wave >> 1) * 64, wn = (wave & 1) * 32;
    const int sr = lane >> 2, sc = (lane & 3) * 8;
    const U16* gA = A + (size_t)(m0 + wave * 32 + sr) * 1024 + sc;
    const U16* gG = Wgu + (size_t)(n0 + wave * 16 + sr) * 1024 + sc;
    const U16* gU = gG + (size_t)4096 * 1024;
    f32x4 ag[4][2] = {}, au[4][2] = {};
    for (int kt = 0; kt < 1024; kt += 64) {
        __syncthreads();
#pragma unroll
        for (int p = 0; p < 2; p++) {
            const int o = kt + p * 32;
            async16(gA + o, &As[p][(wave * 32) * 32]);
            async16(gA + 16 * 1024 + o, &As[p][(wave * 32 + 16) * 32]);
            async16(gG + o, &Gs[p][(wave * 16) * 32]);
            async16(gU + o, &Us[p][(wave * 16) * 32]);
        }
        __syncthreads();
#pragma unroll
        for (int p = 0; p < 2; p++) {
            bf16x8 af[4], bg[2], bu[2];
#pragma unroll
            for (int i = 0; i < 4; i++)
                af[i] = ld8(&As[p][(wm + i * 16 + l16) * 32 + quad * 8]);
#pragma unroll
            for (int i = 0; i < 2; i++) {
                bg[i] = ld8(&Gs[p][(wn + i * 16 + l16) * 32 + quad * 8]);
                bu[i] = ld8(&Us[p][(wn + i * 16 + l16) * 32 + quad * 8]);
            }
#pragma unroll
            for (int mi = 0; mi < 4; mi++)
#pragma unroll
                for (int ni = 0; ni < 2; ni++) {
                    ag[mi][ni] = __builtin_amdgcn_mfma_f32_16x16x32_bf16(af[mi], bg[ni], ag[mi][ni], 0, 0, 0);
                    au[mi][ni] = __builtin_amdgcn_mfma_f32_16x16x32_bf16(af[mi], bu[ni], au[mi][ni], 0, 0, 0);
                }
        }
    }
#pragma unroll
    for (int mi = 0; mi < 4; mi++) {
#pragma unroll
        for (int r = 0; r < 4; r++) {
            int m = m0 + wm + mi * 16 + quad * 4 + r;
#pragma unroll
            for (int ni = 0; ni < 2; ni++) {
                int n = n0 + wn + ni * 16 + l16;
                float g = ag[mi][ni][r], u = au[mi][ni][r];
                float act = g / (1.f + __expf(-g)) * u;
                Cout[(size_t)m * 4096 + n] = f2bf(act);
            }
        }
    }
}

// ---------------- flash self-attention, j-parallel (linear accumulation, no online max)
__global__ __launch_bounds__(256) void flash_self3(const U16* __restrict__ QK, const U16* __restrict__ Vt,
                                                   U16* __restrict__ Og) {
    __shared__ __align__(16) U16 Ps[4 * 1280];
    __shared__ float Ored[4 * 2080];
    __shared__ float Lred[128];
    const int wave = threadIdx.x >> 6, lane = threadIdx.x & 63;
    const int l16 = lane & 15, quad = lane >> 4;
    const int bx = blockIdx.x;
    const int t = 63 - (bx >> 5);
    const int bh = bx & 31, b = bh >> 4, h = bh & 15;
    const int q0 = t * 32;
    const size_t rowQ0 = (size_t)(b * 2048 + q0 + l16) * 2048 + h * 64;
    const size_t rowQ1 = rowQ0 + 16 * 2048;
    bf16x8 aq[2][2];
    aq[0][0] = ld8(QK + rowQ0 + quad * 8);  aq[0][1] = ld8(QK + rowQ0 + 32 + quad * 8);
    aq[1][0] = ld8(QK + rowQ1 + quad * 8);  aq[1][1] = ld8(QK + rowQ1 + 32 + quad * 8);
    const U16* Kbase = QK + (size_t)(b * 2048) * 2048 + 1024 + h * 64;
    const U16* Vbase = Vt + (size_t)(h * 64) * 4096 + b * 2048;
    f32x4 o[2][4] = {};
    float ls[2][4] = {};
    U16* Pw = &Ps[wave * 1280];
    const int prd = l16 * 40 + ((quad ^ (l16 >> 2)) << 3);
    const int jend = q0 + 32;
    for (int j0 = wave * 32; j0 < jend; j0 += 128) {
        const U16* kp = Kbase + (size_t)j0 * 2048;
        bf16x8 b00 = ld8(kp + (size_t)l16 * 2048 + quad * 8);
        bf16x8 b01 = ld8(kp + (size_t)l16 * 2048 + 32 + quad * 8);
        bf16x8 b10 = ld8(kp + (size_t)(16 + l16) * 2048 + quad * 8);
        bf16x8 b11 = ld8(kp + (size_t)(16 + l16) * 2048 + 32 + quad * 8);
        bf16x8 v0 = ld8(Vbase + (size_t)(0  + l16) * 4096 + j0 + quad * 8);
        bf16x8 v1 = ld8(Vbase + (size_t)(16 + l16) * 4096 + j0 + quad * 8);
        bf16x8 v2 = ld8(Vbase + (size_t)(32 + l16) * 4096 + j0 + quad * 8);
        bf16x8 v3 = ld8(Vbase + (size_t)(48 + l16) * 4096 + j0 + quad * 8);
        f32x4 s[2][2] = {};
#pragma unroll
        for (int g = 0; g < 2; g++) {
            s[g][0] = __builtin_amdgcn_mfma_f32_16x16x32_bf16(aq[g][0], b00, s[g][0], 0, 0, 0);
            s[g][0] = __builtin_amdgcn_mfma_f32_16x16x32_bf16(aq[g][1], b01, s[g][0], 0, 0, 0);
            s[g][1] = __builtin_amdgcn_mfma_f32_16x16x32_bf16(aq[g][0], b10, s[g][1], 0, 0, 0);
            s[g][1] = __builtin_amdgcn_mfma_f32_16x16x32_bf16(aq[g][1], b11, s[g][1], 0, 0, 0);
        }
        float p0[2][4], p1[2][4];
        if (j0 + 32 >= jend) {
#pragma unroll
            for (int g = 0; g < 2; g++)
#pragma unroll
                for (int r = 0; r < 4; r++) {
                    int qg = q0 + g * 16 + quad * 4 + r;
                    p0[g][r] = (j0 + l16 <= qg) ? __expf(fminf(s[g][0][r] * 0.125f, 30.f)) : 0.f;
                    p1[g][r] = (j0 + 16 + l16 <= qg) ? __expf(fminf(s[g][1][r] * 0.125f, 30.f)) : 0.f;
                }
        } else {
#pragma unroll
            for (int g = 0; g < 2; g++)
#pragma unroll
                for (int r = 0; r < 4; r++) {
                    p0[g][r] = __expf(fminf(s[g][0][r] * 0.125f, 30.f));
                    p1[g][r] = __expf(fminf(s[g][1][r] * 0.125f, 30.f));
                }
        }
#pragma unroll
        for (int g = 0; g < 2; g++)
#pragma unroll
            for (int r = 0; r < 4; r++) {
                ls[g][r] += p0[g][r] + p1[g][r];
                int row = quad * 4 + r;
                Pw[g * 640 + row * 40 + ((((l16 >> 3) + 0) ^ quad) << 3) + (l16 & 7)] = f2bf_fast(p0[g][r]);
                Pw[g * 640 + row * 40 + ((((l16 >> 3) + 2) ^ quad) << 3) + (l16 & 7)] = f2bf_fast(p1[g][r]);
            }
#pragma unroll
        for (int g = 0; g < 2; g++) {
            bf16x8 ap = ld8(&Pw[g * 640 + prd]);
            o[g][0] = __builtin_amdgcn_mfma_f32_16x16x32_bf16(ap, v0, o[g][0], 0, 0, 0);
            o[g][1] = __builtin_amdgcn_mfma_f32_16x16x32_bf16(ap, v1, o[g][1], 0, 0, 0);
            o[g][2] = __builtin_amdgcn_mfma_f32_16x16x32_bf16(ap, v2, o[g][2], 0, 0, 0);
            o[g][3] = __builtin_amdgcn_mfma_f32_16x16x32_bf16(ap, v3, o[g][3], 0, 0, 0);
        }
    }
    float* Or = &Ored[wave * 2080];
#pragma unroll
    for (int g = 0; g < 2; g++) {
#pragma unroll
        for (int dg = 0; dg < 4; dg++)
#pragma unroll
            for (int r = 0; r < 4; r++)
                Or[(g * 16 + quad * 4 + r) * 65 + dg * 16 + l16] = o[g][dg][r];
#pragma unroll
        for (int r = 0; r < 4; r++) {
            float v = ls[g][r];
            v += __shfl_xor(v, 1); v += __shfl_xor(v, 2);
            v += __shfl_xor(v, 4); v += __shfl_xor(v, 8);
            if (l16 == 0) Lred[wave * 32 + g * 16 + quad * 4 + r] = v;
        }
    }
    __syncthreads();
    const int q = threadIdx.x >> 3, d0 = (threadIdx.x & 7) * 8;
    float l = Lred[q] + Lred[32 + q] + Lred[64 + q] + Lred[96 + q];
    float inv = 1.0f / l;
    us8 outv;
#pragma unroll
    for (int i = 0; i < 8; i++) {
        int idx = q * 65 + d0 + i;
        float s = Ored[idx] + Ored[2080 + idx] + Ored[4160 + idx] + Ored[6240 + idx];
        outv[i] = f2bf(s * inv);
    }
    *(us8*)(Og + (size_t)(b * 2048 + q0 + q) * 1024 + h * 64 + d0) = outv;
}

// ---------------- sliding-window cross attention (9 kv per query)
__global__ __launch_bounds__(256) void cross_attn(const U16* __restrict__ qc, const U16* __restrict__ kvc,
                                                  const int* __restrict__ seg_ids, U16* __restrict__ oc) {
    const int tok = blockIdx.x;
    const int b = tok >> 11;
    const int w = threadIdx.x >> 6, lane = threadIdx.x & 63;
    const int h = blockIdx.y * 4 + w;
    const int seg = seg_ids[tok];
    const size_t qoff = (size_t)tok * 1024 + h * 64 + lane;
    float q = bf2f(qc[qoff]);
    float s[9];
#pragma unroll
    for (int jj = 0; jj < 9; jj++) {
        int j = seg - 8 + jj;
        float sc = -INFINITY;
        if (j >= 0) {
            float kv = bf2f(kvc[((size_t)(b * 512) + j) * 2048 + h * 64 + lane]);
            sc = q * kv;
            sc += __shfl_xor(sc, 1); sc += __shfl_xor(sc, 2); sc += __shfl_xor(sc, 4);
            sc += __shfl_xor(sc, 8); sc += __shfl_xor(sc, 16); sc += __shfl_xor(sc, 32);
            sc *= 0.125f;
        }
        s[jj] = sc;
    }
    float m = s[0];
#pragma unroll
    for (int jj = 1; jj < 9; jj++) m = fmaxf(m, s[jj]);
    float l = 0.f, o = 0.f;
#pragma unroll
    for (int jj = 0; jj < 9; jj++) {
        int j = seg - 8 + jj;
        if (j >= 0) {
            float p = __expf(s[jj] - m);
            l += p;
            o += p * bf2f(kvc[((size_t)(b * 512) + j) * 2048 + 1024 + h * 64 + lane]);
        }
    }
    oc[qoff] = f2bf(o / l);
}

extern "C" void kernel_launch(void* const* d_in, const int* in_sizes, int n_in,
                              void* d_out, int out_size, void* d_ws, size_t ws_size,
                              hipStream_t stream) {
    const float* x      = (const float*)d_in[0];
    const float* memory = (const float*)d_in[1];
    const int*   seg    = (const int*)d_in[2];
    const float* n1w    = (const float*)d_in[3];
    const float* W_dq   = (const float*)d_in[4];
    const float* W_uq   = (const float*)d_in[5];
    const float* W_dkv  = (const float*)d_in[6];
    const float* W_uk   = (const float*)d_in[7];
    const float* W_uv   = (const float*)d_in[8];
    const float* W_os   = (const float*)d_in[9];
    const float* n2w    = (const float*)d_in[10];
    const float* W_qc   = (const float*)d_in[11];
    const float* W_kc   = (const float*)d_in[12];
    const float* W_vc   = (const float*)d_in[13];
    const float* W_oc   = (const float*)d_in[14];
    const float* n3w    = (const float*)d_in[15];
    const float* W_gate = (const float*)d_in[16];
    const float* W_up   = (const float*)d_in[17];
    const float* W_down = (const float*)d_in[18];
    (void)in_sizes; (void)n_in; (void)out_size; (void)ws_size;

    char* ws = (char*)d_ws;
    size_t off = 0;
    auto alloc = [&](size_t bytes) -> void* {
        void* p = ws + off;
        off += (bytes + 255) & ~(size_t)255;
        return p;
    };
    const size_t MB = 1024 * 1024;
    U16* hbuf     = (U16*)alloc(8 * MB);
    float* x1     = (float*)alloc(16 * MB);
    float* x2     = (float*)alloc(16 * MB);
    float* cq32   = (float*)alloc(8 * MB);          // 4 split-K fp32 partials [4][4096*128]
    U16* Wt_dqkv  = (U16*)alloc(128 * 1024 * 2);
    U16* Wt_uqk   = (U16*)alloc(2048 * 128 * 2);
    U16* Wt_uv    = (U16*)alloc(1024 * 128 * 2);
    U16* Wt_os    = (U16*)alloc(1024 * 1024 * 2);
    U16* Wt_qc    = (U16*)alloc(1024 * 1024 * 2);
    U16* Wt_kvc   = (U16*)alloc((size_t)2048 * 1024 * 2);
    U16* Wt_oc    = (U16*)alloc(1024 * 1024 * 2);
    U16* Wt_gu    = (U16*)alloc((size_t)8192 * 1024 * 2);
    U16* Wt_down  = (U16*)alloc((size_t)1024 * 4096 * 2);
    U16* mem_bf   = (U16*)alloc(1024 * 1024 * 2);
    char* arena   = ws + off;
    // phase 1
    U16* cq  = (U16*)(arena);                  // [4096][128]
    U16* qkb = (U16*)(arena + 1 * MB);         // [4096][2048]
    U16* vt  = (U16*)(arena + 17 * MB);        // [1024][4096]
    U16* ob  = (U16*)(arena + 25 * MB);        // [4096][1024]
    // phase 2
    U16* qcb  = (U16*)(arena);                 // [4096][1024]
    U16* kvcb = (U16*)(arena + 8 * MB);        // [1024][2048]
    U16* ocb  = (U16*)(arena + 12 * MB);       // [4096][1024]
    // phase 3
    U16* gact = (U16*)(arena);                 // [4096][4096]

    // ---- merged weight prep
    WTable T;
    int i = 0;
    auto ent = [&](const float* s, U16* d, int K, int N, int Kpad, int Npad, int koff, int noff) {
        T.e[i++] = WEnt{s, d, K, N, Kpad, Npad, koff, noff, (Kpad >> 5) * (Npad >> 5)};
    };
    ent(W_dq,   Wt_dqkv, 1024, 32,   1024, 32,   0,  0);
    ent(W_dkv,  Wt_dqkv, 1024, 64,   1024, 96,   0,  32);
    ent(W_uq,   Wt_uqk,  32,   1024, 128,  1024, 0,  0);
    ent(W_uk,   Wt_uqk,  64,   1024, 128,  1024, 32, 1024);
    ent(W_uv,   Wt_uv,   64,   1024, 128,  1024, 32, 0);
    ent(W_os,   Wt_os,   1024, 1024, 1024, 1024, 0,  0);
    ent(W_qc,   Wt_qc,   1024, 1024, 1024, 1024, 0,  0);
    ent(W_kc,   Wt_kvc,  1024, 1024, 1024, 1024, 0,  0);
    ent(W_vc,   Wt_kvc,  1024, 1024, 1024, 1024, 0,  1024);
    ent(W_oc,   Wt_oc,   1024, 1024, 1024, 1024, 0,  0);
    ent(W_gate, Wt_gu,   1024, 4096, 1024, 4096, 0,  0);
    ent(W_up,   Wt_gu,   1024, 4096, 1024, 4096, 0,  4096);
    ent(W_down, Wt_down, 4096, 1024, 4096, 1024, 0,  0);
    int total_tiles = 0;
    for (int j = 0; j < 13; j++) total_tiles += T.e[j].tiles;
    wtrans_all<<<total_tiles, 256, 0, stream>>>(T);
    f2bf_k<<<1024, 256, 0, stream>>>(memory, mem_bf, 1024 * 1024);

    // ---- phase 1: self-attention block
    rmsnorm_k<<<4096, 256, 0, stream>>>(x, n1w, hbuf);
    gemm_m64<5><<<dim3(1, 64, 4), 256, 0, stream>>>(hbuf, Wt_dqkv, cq32, nullptr, 4096, 128, 256, 1024, 1024, 128);
    cq_reduce<<<512, 256, 0, stream>>>(cq32, cq);
    qkuv_gemm<<<dim3(24, 32), 256, 0, stream>>>(cq, Wt_uqk, Wt_uv, qkb, vt);
    flash_self3<<<2048, 256, 0, stream>>>(qkb, vt, ob);
    gemm_m64<1><<<dim3(8, 64), 256, 0, stream>>>(ob, Wt_os, x1, x, 4096, 1024, 1024, 1024, 1024, 1024);

    // ---- phase 2: cross attention block
    rmsnorm_k<<<4096, 256, 0, stream>>>(x1, n2w, hbuf);
    qckv_gemm<<<768, 256, 0, stream>>>(hbuf, Wt_qc, mem_bf, Wt_kvc, qcb, kvcb);
    cross_attn<<<dim3(4096, 4), 256, 0, stream>>>(qcb, kvcb, seg, ocb);
    gemm_m64<1><<<dim3(8, 64), 256, 0, stream>>>(ocb, Wt_oc, x2, x1, 4096, 1024, 1024, 1024, 1024, 1024);

    // ---- phase 3: FFN (fused gate+up+silu, then down)
    rmsnorm_k<<<4096, 256, 0, stream>>>(x2, n3w, hbuf);
    ffn1_fused<<<dim3(64, 32), 256, 0, stream>>>(hbuf, Wt_gu, gact);
    gemm_m64<1><<<dim3(8, 64), 256, 0, stream>>>(gact, Wt_down, (float*)d_out, x2, 4096, 1024, 4096, 4096, 4096, 1024);
}